// Round 2
// baseline (384.120 us; speedup 1.0000x reference)
//
#include <hip/hip_runtime.h>

// ---------------------------------------------------------------------------
// LabelSimilarity: match[b,l] = max(-1, max_{s,v} cos(embed[s,b,:], label[l,v,:]))
// S=256 B=128 D=768 ; L=200 V=8 ; out [128,200] fp32
//
// R2: XOR-swizzled LDS tiles (kills the 8-way ds_read_b128 bank conflicts:
// slot (row,c) holds global chunk c ^ ((row>>1)&3), baked into the
// global_load_lds gather addresses so coalescing is preserved), and the
// epilogue writes atomics directly from shuffle-reduced lanes (no LDS
// round-trip, one fewer barrier).
// ---------------------------------------------------------------------------

typedef __bf16 bf16x8 __attribute__((ext_vector_type(8)));
typedef float  f32x4  __attribute__((ext_vector_type(4)));

#define GLD16(gp, lp) __builtin_amdgcn_global_load_lds(                        \
    (__attribute__((address_space(1))) void*)(gp),                             \
    (__attribute__((address_space(3))) void*)(lp), 16, 0, 0)

__device__ __forceinline__ unsigned short f32_to_bf16_rne(float x) {
  unsigned u = __float_as_uint(x);
  u += 0x7fffu + ((u >> 16) & 1u);
  return (unsigned short)(u >> 16);
}

// One wave per row: L2-normalize a 768-elem fp32 row -> bf16. Rows >= nsrc are
// zero pad rows (for N padding 1600->1664).
__global__ void __launch_bounds__(256) normalize_rows(
    const float* __restrict__ src, unsigned short* __restrict__ dst,
    int nsrc, int ndst) {
  int row  = blockIdx.x * 4 + (threadIdx.x >> 6);
  int lane = threadIdx.x & 63;
  if (row >= ndst) return;
  ushort4* drow = (ushort4*)(dst + (size_t)row * 768);
  if (row >= nsrc) {
    ushort4 z; z.x = z.y = z.z = z.w = 0;
#pragma unroll
    for (int t = 0; t < 3; ++t) drow[lane + 64 * t] = z;
    return;
  }
  const float4* srow = (const float4*)(src + (size_t)row * 768);
  float4 v[3];
  float ss = 0.f;
#pragma unroll
  for (int t = 0; t < 3; ++t) {
    v[t] = srow[lane + 64 * t];
    ss += v[t].x * v[t].x + v[t].y * v[t].y + v[t].z * v[t].z + v[t].w * v[t].w;
  }
#pragma unroll
  for (int off = 1; off < 64; off <<= 1) ss += __shfl_xor(ss, off);
  float rinv = rsqrtf(fmaxf(ss, 1e-12f));
#pragma unroll
  for (int t = 0; t < 3; ++t) {
    ushort4 h;
    h.x = f32_to_bf16_rne(v[t].x * rinv);
    h.y = f32_to_bf16_rne(v[t].y * rinv);
    h.z = f32_to_bf16_rne(v[t].z * rinv);
    h.w = f32_to_bf16_rne(v[t].w * rinv);
    drow[lane + 64 * t] = h;
  }
}

// key(-1.0f): u=0xBF800000 (negative) -> ~u = 0x407FFFFF
__global__ void __launch_bounds__(256) init_out_keys(unsigned* outU, int n) {
  int i = blockIdx.x * 256 + threadIdx.x;
  if (i < n) outU[i] = 0x407FFFFFu;
}

// GEMM + fused max epilogue. Block = (n-tile bx in [0,13), s = by in [0,256)).
// A-tile rows = s*128 + b (all b), so M-max == s-max (cross-block atomics).
__global__ void __launch_bounds__(256) gemm_max_kernel(
    const unsigned short* __restrict__ Ap,   // [32768][768] bf16 (normalized)
    const unsigned short* __restrict__ Bp,   // [1664][768]  bf16 (normalized)
    unsigned* __restrict__ outU) {           // [128*200] monotonic keys
  __shared__ unsigned short As[4096];  // [128][32] bf16, chunk-swizzled
  __shared__ unsigned short Bs[4096];  // [128][32] bf16, chunk-swizzled

  const int t    = threadIdx.x;
  const int lane = t & 63;
  const int w    = t >> 6;             // wave 0..3
  const int s    = blockIdx.y;
  const int n0   = blockIdx.x * 128;

  // --- staging: LDS slot index == t (16B each). slot (row=t>>2, cs=t&3)
  //     holds global chunk cg = cs ^ ((row>>1)&3) of that row. Swizzle stays
  //     inside the row's 64B line -> coalescing preserved.
  const int srow = t >> 2;
  const int cg   = (t & 3) ^ ((t >> 3) & 3);
  const char* gA = (const char*)(Ap + (size_t)(s * 128) * 768);
  const char* gB = (const char*)(Bp + (size_t)n0 * 768);
  const char* ga0 = gA + srow * 1536 + cg * 16;          // rows 0..63
  const char* ga1 = ga0 + 64 * 1536;                     // rows 64..127
  const char* gb0 = gB + srow * 1536 + cg * 16;
  const char* gb1 = gb0 + 64 * 1536;
  char* lA0 = (char*)As + w * 1024;
  char* lA1 = (char*)As + 4096 + w * 1024;
  char* lB0 = (char*)Bs + w * 1024;
  char* lB1 = (char*)Bs + 4096 + w * 1024;

  // --- wave tile: 2x2 waves, each 64x64 = 4x4 MFMA tiles of 16x16 ---
  const int wm  = (w >> 1) * 64;
  const int wn  = (w & 1) * 64;
  const int r16 = lane & 15;
  // fragment read: chunk c = lane>>4, swizzled slot = c ^ ((r16>>1)&3)
  const int swz  = (((lane >> 4) ^ ((r16 >> 1) & 3)) * 16);   // bytes
  const int aoffB = (wm + r16) * 64 + swz;  // byte offset in As
  const int boffB = (wn + r16) * 64 + swz;  // byte offset in Bs

  f32x4 acc[4][4];
#pragma unroll
  for (int i = 0; i < 4; ++i)
#pragma unroll
    for (int j = 0; j < 4; ++j)
      acc[i][j] = (f32x4){0.f, 0.f, 0.f, 0.f};

  for (int kk = 0; kk < 24; ++kk) {    // K = 768 = 24 * 32
    GLD16(ga0, lA0); GLD16(ga1, lA1);
    GLD16(gb0, lB0); GLD16(gb1, lB1);
    ga0 += 64; ga1 += 64; gb0 += 64; gb1 += 64;
    __syncthreads();                   // drains vmcnt -> LDS tiles ready
    bf16x8 af[4], bfr[4];
#pragma unroll
    for (int i = 0; i < 4; ++i)
      af[i] = *(const bf16x8*)((const char*)As + aoffB + i * 1024);
#pragma unroll
    for (int j = 0; j < 4; ++j)
      bfr[j] = *(const bf16x8*)((const char*)Bs + boffB + j * 1024);
#pragma unroll
    for (int i = 0; i < 4; ++i)
#pragma unroll
      for (int j = 0; j < 4; ++j)
        acc[i][j] = __builtin_amdgcn_mfma_f32_16x16x32_bf16(
            af[i], bfr[j], acc[i][j], 0, 0, 0);
    __syncthreads();                   // protect LDS before next stage
  }

  // --- epilogue: acc is cos. C/D layout: col=lane&15, row=(lane>>4)*4+r ---
  // max over v (col groups of 8) via shuffle-xor 1,2,4; writer lanes issue
  // atomicMax on monotonic keys directly (no LDS round-trip).
  const int lbase = blockIdx.x * 16;
  const int rowg  = lane >> 4;         // 0..3
  const int lbit  = (lane >> 3) & 1;   // which l within the 16-wide tile
  const bool writer = (lane & 7) == 0;
#pragma unroll
  for (int i = 0; i < 4; ++i) {
#pragma unroll
    for (int j = 0; j < 4; ++j) {
#pragma unroll
      for (int r = 0; r < 4; ++r) {
        float vv = acc[i][j][r];
        vv = fmaxf(vv, __shfl_xor(vv, 1));
        vv = fmaxf(vv, __shfl_xor(vv, 2));
        vv = fmaxf(vv, __shfl_xor(vv, 4));
        if (writer) {
          int b = wm + i * 16 + rowg * 4 + r;
          int l = lbase + (wn >> 3) + j * 2 + lbit;
          if (l < 200) {
            unsigned u   = __float_as_uint(vv);
            unsigned key = (u & 0x80000000u) ? ~u : (u | 0x80000000u);
            atomicMax(&outU[b * 200 + l], key);
          }
        }
      }
    }
  }
}

__global__ void __launch_bounds__(256) finalize_out(
    const unsigned* __restrict__ outU, float* __restrict__ out, int n) {
  int i = blockIdx.x * 256 + threadIdx.x;
  if (i < n) {
    unsigned key = outU[i];
    unsigned u = (key & 0x80000000u) ? (key & 0x7FFFFFFFu) : ~key;
    out[i] = fmaxf(__uint_as_float(u), -1.0f);  // init key was -1.0 already
  }
}

// Brute-force fp32 fallback (only if ws_size is too small): one block per (b,l).
__global__ void __launch_bounds__(256) fallback_kernel(
    const float* __restrict__ embed, const float* __restrict__ label,
    float* __restrict__ out) {
  int b = blockIdx.x, l = blockIdx.y, t = threadIdx.x;
  float m = -1.0f;
  for (int p = t; p < 2048; p += 256) {
    int s = p >> 3, v = p & 7;
    const float* e = embed + (size_t)(s * 128 + b) * 768;
    const float* q = label + (size_t)(l * 8 + v) * 768;
    float dot = 0.f, ne = 0.f, nl = 0.f;
    for (int d = 0; d < 768; ++d) {
      float x = e[d], y = q[d];
      dot += x * y; ne += x * x; nl += y * y;
    }
    m = fmaxf(m, dot / fmaxf(sqrtf(ne) * sqrtf(nl), 1e-8f));
  }
  for (int off = 1; off < 64; off <<= 1) m = fmaxf(m, __shfl_xor(m, off));
  __shared__ float wmax[4];
  if ((t & 63) == 0) wmax[t >> 6] = m;
  __syncthreads();
  if (t == 0)
    out[b * 200 + l] = fmaxf(fmaxf(wmax[0], wmax[1]), fmaxf(wmax[2], wmax[3]));
}

extern "C" void kernel_launch(void* const* d_in, const int* in_sizes, int n_in,
                              void* d_out, int out_size, void* d_ws, size_t ws_size,
                              hipStream_t stream) {
  const float* embed = (const float*)d_in[0];   // [256,128,768]
  const float* label = (const float*)d_in[1];   // [200,8,768]
  float* out = (float*)d_out;                   // [128,200]

  const size_t szA = (size_t)32768 * 768 * 2;   // 50,331,648
  const size_t szB = (size_t)1664 * 768 * 2;    //  2,555,904
  const size_t szU = (size_t)25600 * 4;         //    102,400

  if (ws_size < szA + szB + szU) {
    dim3 g(128, 200);
    fallback_kernel<<<g, 256, 0, stream>>>(embed, label, out);
    return;
  }

  unsigned short* Ap  = (unsigned short*)d_ws;
  unsigned short* Bp  = (unsigned short*)((char*)d_ws + szA);
  unsigned*       oU  = (unsigned*)((char*)d_ws + szA + szB);

  normalize_rows<<<32768 / 4, 256, 0, stream>>>(embed, Ap, 32768, 32768);
  normalize_rows<<<1664 / 4, 256, 0, stream>>>(label, Bp, 1600, 1664);
  init_out_keys<<<100, 256, 0, stream>>>(oU, 25600);
  dim3 g(13, 256);  // 13 n-tiles x 256 s  = 3328 blocks (~13/CU)
  gemm_max_kernel<<<g, 256, 0, stream>>>(Ap, Bp, oU);
  finalize_out<<<100, 256, 0, stream>>>(oU, out, 25600);
}

// Round 3
// 302.780 us; speedup vs baseline: 1.2686x; 1.2686x over previous
//
#include <hip/hip_runtime.h>

// ---------------------------------------------------------------------------
// LabelSimilarity: match[b,l] = max(-1, max_{s,v} cos(embed[s,b,:], label[l,v,:]))
// S=256 B=128 D=768 ; L=200 V=8 ; out [128,200] fp32
//
// R3: atomic-free epilogue. Stage-1 gemm blocks write private [128b x 16l]
// max tiles to scratch (coalesced float4, 27 MB total); two small reduce
// kernels fold over s. LDS chunk-swizzle from R2 kept (bank conflicts = 0).
// R2 lesson: 6.8M contended device atomics cost ~60+ us — removed entirely.
// ---------------------------------------------------------------------------

typedef __bf16 bf16x8 __attribute__((ext_vector_type(8)));
typedef float  f32x4  __attribute__((ext_vector_type(4)));

#define GLD16(gp, lp) __builtin_amdgcn_global_load_lds(                        \
    (__attribute__((address_space(1))) void*)(gp),                             \
    (__attribute__((address_space(3))) void*)(lp), 16, 0, 0)

__device__ __forceinline__ unsigned short f32_to_bf16_rne(float x) {
  unsigned u = __float_as_uint(x);
  u += 0x7fffu + ((u >> 16) & 1u);
  return (unsigned short)(u >> 16);
}

// One wave per row: L2-normalize a 768-elem fp32 row -> bf16. Rows >= nsrc are
// zero pad rows (for N padding 1600->1664).
__global__ void __launch_bounds__(256) normalize_rows(
    const float* __restrict__ src, unsigned short* __restrict__ dst,
    int nsrc, int ndst) {
  int row  = blockIdx.x * 4 + (threadIdx.x >> 6);
  int lane = threadIdx.x & 63;
  if (row >= ndst) return;
  ushort4* drow = (ushort4*)(dst + (size_t)row * 768);
  if (row >= nsrc) {
    ushort4 z; z.x = z.y = z.z = z.w = 0;
#pragma unroll
    for (int t = 0; t < 3; ++t) drow[lane + 64 * t] = z;
    return;
  }
  const float4* srow = (const float4*)(src + (size_t)row * 768);
  float4 v[3];
  float ss = 0.f;
#pragma unroll
  for (int t = 0; t < 3; ++t) {
    v[t] = srow[lane + 64 * t];
    ss += v[t].x * v[t].x + v[t].y * v[t].y + v[t].z * v[t].z + v[t].w * v[t].w;
  }
#pragma unroll
  for (int off = 1; off < 64; off <<= 1) ss += __shfl_xor(ss, off);
  float rinv = rsqrtf(fmaxf(ss, 1e-12f));
#pragma unroll
  for (int t = 0; t < 3; ++t) {
    ushort4 h;
    h.x = f32_to_bf16_rne(v[t].x * rinv);
    h.y = f32_to_bf16_rne(v[t].y * rinv);
    h.z = f32_to_bf16_rne(v[t].z * rinv);
    h.w = f32_to_bf16_rne(v[t].w * rinv);
    drow[lane + 64 * t] = h;
  }
}

// GEMM + per-block max tile. Block = (n-tile bx in [0,13), s = by in [0,256)).
// Writes scratch[(bx*256+s)*2048 + b*16 + ll]  (b in [0,128), ll in [0,16)).
__global__ void __launch_bounds__(256) gemm_store_kernel(
    const unsigned short* __restrict__ Ap,   // [32768][768] bf16 (normalized)
    const unsigned short* __restrict__ Bp,   // [1664][768]  bf16 (normalized)
    float* __restrict__ scratch) {
  __shared__ char smem[16384];
  unsigned short* As = (unsigned short*)smem;          // [128][32] swizzled
  unsigned short* Bs = (unsigned short*)(smem + 8192); // [128][32] swizzled

  const int t    = threadIdx.x;
  const int lane = t & 63;
  const int w    = t >> 6;             // wave 0..3
  const int s    = blockIdx.y;
  const int n0   = blockIdx.x * 128;

  // staging: LDS slot == t (16B). slot (row=t>>2, cs=t&3) holds global chunk
  // cg = cs ^ ((row>>1)&3) (swizzle stays inside the row's 64B line).
  const int srow = t >> 2;
  const int cg   = (t & 3) ^ ((t >> 3) & 3);
  const char* gA = (const char*)(Ap + (size_t)(s * 128) * 768);
  const char* gB = (const char*)(Bp + (size_t)n0 * 768);
  const char* ga0 = gA + srow * 1536 + cg * 16;          // rows 0..63
  const char* ga1 = ga0 + 64 * 1536;                     // rows 64..127
  const char* gb0 = gB + srow * 1536 + cg * 16;
  const char* gb1 = gb0 + 64 * 1536;
  char* lA0 = (char*)As + w * 1024;
  char* lA1 = (char*)As + 4096 + w * 1024;
  char* lB0 = (char*)Bs + w * 1024;
  char* lB1 = (char*)Bs + 4096 + w * 1024;

  // wave tile: 2x2 waves, each 64x64 = 4x4 MFMA tiles of 16x16
  const int wm  = (w >> 1) * 64;
  const int wn  = (w & 1) * 64;
  const int r16 = lane & 15;
  const int swz  = (((lane >> 4) ^ ((r16 >> 1) & 3)) * 16);   // bytes
  const int aoffB = (wm + r16) * 64 + swz;
  const int boffB = (wn + r16) * 64 + swz;

  f32x4 acc[4][4];
#pragma unroll
  for (int i = 0; i < 4; ++i)
#pragma unroll
    for (int j = 0; j < 4; ++j)
      acc[i][j] = (f32x4){0.f, 0.f, 0.f, 0.f};

  for (int kk = 0; kk < 24; ++kk) {    // K = 768 = 24 * 32
    GLD16(ga0, lA0); GLD16(ga1, lA1);
    GLD16(gb0, lB0); GLD16(gb1, lB1);
    ga0 += 64; ga1 += 64; gb0 += 64; gb1 += 64;
    __syncthreads();                   // drains vmcnt -> LDS tiles ready
    bf16x8 af[4], bfr[4];
#pragma unroll
    for (int i = 0; i < 4; ++i)
      af[i] = *(const bf16x8*)((const char*)As + aoffB + i * 1024);
#pragma unroll
    for (int j = 0; j < 4; ++j)
      bfr[j] = *(const bf16x8*)((const char*)Bs + boffB + j * 1024);
#pragma unroll
    for (int i = 0; i < 4; ++i)
#pragma unroll
      for (int j = 0; j < 4; ++j)
        acc[i][j] = __builtin_amdgcn_mfma_f32_16x16x32_bf16(
            af[i], bfr[j], acc[i][j], 0, 0, 0);
    __syncthreads();                   // protect LDS before next stage
  }

  // epilogue: acc is cos. C/D: col=lane&15, row=(lane>>4)*4+r.
  // max over v (col groups of 8) via shuffle; compact via LDS (stride 17,
  // conflict-free), then coalesced float4 stores to private scratch tile.
  float* red = (float*)smem;           // [128][17] floats = 8704 B
  const int rowg  = lane >> 4;
  const int lbit  = (lane >> 3) & 1;
  const bool writer = (lane & 7) == 0;
#pragma unroll
  for (int i = 0; i < 4; ++i) {
#pragma unroll
    for (int j = 0; j < 4; ++j) {
#pragma unroll
      for (int r = 0; r < 4; ++r) {
        float vv = acc[i][j][r];
        vv = fmaxf(vv, __shfl_xor(vv, 1));
        vv = fmaxf(vv, __shfl_xor(vv, 2));
        vv = fmaxf(vv, __shfl_xor(vv, 4));
        if (writer) {
          int b  = wm + i * 16 + rowg * 4 + r;
          int ll = (wn >> 3) + j * 2 + lbit;
          red[b * 17 + ll] = vv;
        }
      }
    }
  }
  __syncthreads();
  // thread t -> elements e = t*8 .. t*8+7 ; b = t>>1, ll = (t&1)*8 + k
  {
    const int b  = t >> 1;
    const int l8 = (t & 1) * 8;
    float4 p0, p1;
    p0.x = red[b * 17 + l8 + 0]; p0.y = red[b * 17 + l8 + 1];
    p0.z = red[b * 17 + l8 + 2]; p0.w = red[b * 17 + l8 + 3];
    p1.x = red[b * 17 + l8 + 4]; p1.y = red[b * 17 + l8 + 5];
    p1.z = red[b * 17 + l8 + 6]; p1.w = red[b * 17 + l8 + 7];
    float4* g = (float4*)(scratch + ((size_t)(blockIdx.x * 256 + s)) * 2048 + t * 8);
    g[0] = p0; g[1] = p1;
  }
}

// reduce1: block (bx, sg) folds s in [sg*8, sg*8+8) -> partial[bx][sg][2048]
__global__ void __launch_bounds__(256) reduce1_kernel(
    const float* __restrict__ scratch, float* __restrict__ partial) {
  const int t  = threadIdx.x;
  const int bx = blockIdx.x;
  const int sg = blockIdx.y;
  const float* base = scratch + ((size_t)(bx * 256 + sg * 8)) * 2048 + t * 8;
  float4 m0 = ((const float4*)base)[0];
  float4 m1 = ((const float4*)base)[1];
  for (int ss = 1; ss < 8; ++ss) {
    const float4* p = (const float4*)(base + (size_t)ss * 2048);
    float4 a = p[0], b = p[1];
    m0.x = fmaxf(m0.x, a.x); m0.y = fmaxf(m0.y, a.y);
    m0.z = fmaxf(m0.z, a.z); m0.w = fmaxf(m0.w, a.w);
    m1.x = fmaxf(m1.x, b.x); m1.y = fmaxf(m1.y, b.y);
    m1.z = fmaxf(m1.z, b.z); m1.w = fmaxf(m1.w, b.w);
  }
  float4* o = (float4*)(partial + ((size_t)(bx * 32 + sg)) * 2048 + t * 8);
  o[0] = m0; o[1] = m1;
}

// reduce2: out[b][l] = max(-1, max over 32 partials)
__global__ void __launch_bounds__(256) reduce2_kernel(
    const float* __restrict__ partial, float* __restrict__ out) {
  int idx = blockIdx.x * 256 + threadIdx.x;   // 0 .. 26623
  if (idx >= 13 * 2048) return;
  int bx = idx >> 11;
  int e  = idx & 2047;
  int b  = e >> 4;
  int ll = e & 15;
  int l  = bx * 16 + ll;
  if (l >= 200) return;
  float m = -1.0f;
  const float* p = partial + (size_t)(bx * 32) * 2048 + e;
  for (int c = 0; c < 32; ++c) m = fmaxf(m, p[(size_t)c * 2048]);
  out[b * 200 + l] = m;
}

// Brute-force fp32 fallback (only if ws_size is too small): one block per (b,l).
__global__ void __launch_bounds__(256) fallback_kernel(
    const float* __restrict__ embed, const float* __restrict__ label,
    float* __restrict__ out) {
  int b = blockIdx.x, l = blockIdx.y, t = threadIdx.x;
  float m = -1.0f;
  for (int p = t; p < 2048; p += 256) {
    int s = p >> 3, v = p & 7;
    const float* e = embed + (size_t)(s * 128 + b) * 768;
    const float* q = label + (size_t)(l * 8 + v) * 768;
    float dot = 0.f, ne = 0.f, nl = 0.f;
    for (int d = 0; d < 768; ++d) {
      float x = e[d], y = q[d];
      dot += x * y; ne += x * x; nl += y * y;
    }
    m = fmaxf(m, dot / fmaxf(sqrtf(ne) * sqrtf(nl), 1e-8f));
  }
  for (int off = 1; off < 64; off <<= 1) m = fmaxf(m, __shfl_xor(m, off));
  __shared__ float wmax[4];
  if ((t & 63) == 0) wmax[t >> 6] = m;
  __syncthreads();
  if (t == 0)
    out[b * 200 + l] = fmaxf(fmaxf(wmax[0], wmax[1]), fmaxf(wmax[2], wmax[3]));
}

extern "C" void kernel_launch(void* const* d_in, const int* in_sizes, int n_in,
                              void* d_out, int out_size, void* d_ws, size_t ws_size,
                              hipStream_t stream) {
  const float* embed = (const float*)d_in[0];   // [256,128,768]
  const float* label = (const float*)d_in[1];   // [200,8,768]
  float* out = (float*)d_out;                   // [128,200]

  const size_t szA = (size_t)32768 * 768 * 2;        // 50,331,648
  const size_t szB = (size_t)1664 * 768 * 2;         //  2,555,904
  const size_t szS = (size_t)13 * 256 * 2048 * 4;    // 27,262,976
  const size_t szP = (size_t)13 * 32 * 2048 * 4;     //  3,407,872

  if (ws_size < szA + szB + szS + szP) {
    dim3 g(128, 200);
    fallback_kernel<<<g, 256, 0, stream>>>(embed, label, out);
    return;
  }

  unsigned short* Ap = (unsigned short*)d_ws;
  unsigned short* Bp = (unsigned short*)((char*)d_ws + szA);
  float* scratch     = (float*)((char*)d_ws + szA + szB);
  float* partial     = (float*)((char*)d_ws + szA + szB + szS);

  normalize_rows<<<32768 / 4, 256, 0, stream>>>(embed, Ap, 32768, 32768);
  normalize_rows<<<1664 / 4, 256, 0, stream>>>(label, Bp, 1600, 1664);
  dim3 g(13, 256);  // 13 n-tiles x 256 s = 3328 blocks
  gemm_store_kernel<<<g, 256, 0, stream>>>(Ap, Bp, scratch);
  dim3 r1(13, 32);
  reduce1_kernel<<<r1, 256, 0, stream>>>(scratch, partial);
  reduce2_kernel<<<104, 256, 0, stream>>>(partial, out);
}